// Round 4
// baseline (917.144 us; speedup 1.0000x reference)
//
#include <hip/hip_runtime.h>

#define BB 2048   // batch
#define TT 512    // time steps
#define II 64     // input features
#define XWS 12    // floats per (b,t): 3 x (r,z,n,pad), pre-scaled for exp2

#define LOG2E 1.44269504088896340736f

__device__ __forceinline__ float fexp2(float x) {
#if __has_builtin(__builtin_amdgcn_exp2f)
    return __builtin_amdgcn_exp2f(x);
#else
    return __expf(x * 0.69314718055994531f);
#endif
}
__device__ __forceinline__ float frcp(float x) {
#if __has_builtin(__builtin_amdgcn_rcpf)
    return __builtin_amdgcn_rcpf(x);
#else
    return __fdividef(1.f, x);
#endif
}

// quad broadcasts: every lane gets lane {0,1,2} of its 4-lane quad
#define QB0(v) __int_as_float(__builtin_amdgcn_mov_dpp(__float_as_int(v), 0x00, 0xF, 0xF, 1))
#define QB1(v) __int_as_float(__builtin_amdgcn_mov_dpp(__float_as_int(v), 0x55, 0xF, 0xF, 1))
#define QB2(v) __int_as_float(__builtin_amdgcn_mov_dpp(__float_as_int(v), 0xAA, 0xF, 0xF, 1))

// ---------------------------------------------------------------------------
// K1: xw[b*512+t][4j+c] = scale_c * (b_ih0[c*3+j] + sum_i x[b,t,i] W_ih0[c*3+j,i])
// 4 rows per thread to amortize the LDS weight reads; lanes map to consecutive
// rows (t-fast) so each wave reads contiguous 16KB windows of x.
// ---------------------------------------------------------------------------
__global__ __launch_bounds__(256, 4) void xw_kernel(
    const float* __restrict__ x, const float* __restrict__ W_ih0,
    const float* __restrict__ b_ih0, float* __restrict__ xw)
{
    __shared__ float wt[II * XWS];   // [i][4j+c], pre-scaled
    __shared__ float bias[XWS];
    const int tid = threadIdx.x;

    for (int idx = tid; idx < 9 * II; idx += 256) {
        int i = idx & 63, g = idx >> 6;     // W_ih0 row g = c*3 + j
        int c = g / 3, j = g - c * 3;
        float sc = (c == 2) ? (2.0f * LOG2E) : (-LOG2E);
        wt[i * XWS + j * 4 + c] = W_ih0[idx] * sc;
    }
    if (tid < XWS) {
        int j = tid >> 2, c = tid & 3;
        float v = 0.f;
        if (c < 3) {
            float sc = (c == 2) ? (2.0f * LOG2E) : (-LOG2E);
            v = b_ih0[c * 3 + j] * sc;
        }
        bias[tid] = v;
    }
    __syncthreads();

    const int R0 = blockIdx.x * 1024 + tid;   // this thread: rows R0 + 256*r
    const float* xr = x + (size_t)R0 * II;

    float a[4][XWS];
    {
        float bb[XWS];
#pragma unroll
        for (int u = 0; u < XWS; ++u) bb[u] = bias[u];
#pragma unroll
        for (int r = 0; r < 4; ++r)
#pragma unroll
            for (int u = 0; u < XWS; ++u) a[r][u] = bb[u];
    }

#pragma unroll
    for (int i0 = 0; i0 < II; i0 += 4) {
        float4 xv[4];
#pragma unroll
        for (int r = 0; r < 4; ++r)
            xv[r] = *(const float4*)(xr + (size_t)r * 256 * II + i0);
#pragma unroll
        for (int d = 0; d < 4; ++d) {
            const float4* w4 = (const float4*)&wt[(i0 + d) * XWS];
            float4 w0 = w4[0], w1 = w4[1], w2 = w4[2];
#pragma unroll
            for (int r = 0; r < 4; ++r) {
                float v = (d == 0) ? xv[r].x : (d == 1) ? xv[r].y
                        : (d == 2) ? xv[r].z : xv[r].w;
                a[r][0]  = fmaf(v, w0.x, a[r][0]);
                a[r][1]  = fmaf(v, w0.y, a[r][1]);
                a[r][2]  = fmaf(v, w0.z, a[r][2]);
                a[r][4]  = fmaf(v, w1.x, a[r][4]);
                a[r][5]  = fmaf(v, w1.y, a[r][5]);
                a[r][6]  = fmaf(v, w1.z, a[r][6]);
                a[r][8]  = fmaf(v, w2.x, a[r][8]);
                a[r][9]  = fmaf(v, w2.y, a[r][9]);
                a[r][10] = fmaf(v, w2.z, a[r][10]);
            }
        }
    }

#pragma unroll
    for (int r = 0; r < 4; ++r) {
        float* o = xw + ((size_t)R0 + r * 256) * XWS;
        *(float4*)(o + 0) = make_float4(a[r][0], a[r][1], a[r][2], 0.f);
        *(float4*)(o + 4) = make_float4(a[r][4], a[r][5], a[r][6], 0.f);
        *(float4*)(o + 8) = make_float4(a[r][8], a[r][9], a[r][10], 0.f);
    }
}

// ---------------------------------------------------------------------------
// K2: fused 2-layer GRU recurrence. 4 lanes per sequence, 64-thread blocks,
// launch_bounds(64,1) so the compiler has ~500 VGPRs (no spills). 8-deep
// named-register prefetch ring: each R is reloaded immediately after its use.
// ---------------------------------------------------------------------------
__global__ __launch_bounds__(64, 1) void gru_rec(
    const float* __restrict__ xw,
    const float* __restrict__ W_hh0, const float* __restrict__ b_hh0,
    const float* __restrict__ W_ih1, const float* __restrict__ b_ih1,
    const float* __restrict__ W_hh1, const float* __restrict__ b_hh1,
    float* __restrict__ out)
{
    const int tid = threadIdx.x;
    const int j   = tid & 3;
    const int jj  = (j < 3) ? j : 2;                   // lane 3 mirrors lane 2
    const int s   = (blockIdx.x * 64 + tid) >> 2;      // sequence index

    // per-lane pre-scaled weights (rows c*3+jj), c in {r,z,n}
    float wh0[3][3], wi1[3][3], wh1[3][3], bh0[3], bi1[3], bh1[3];
#pragma unroll
    for (int c = 0; c < 3; ++c) {
        float sc = (c == 2) ? (2.0f * LOG2E) : (-LOG2E);
        int row = c * 3 + jj;
#pragma unroll
        for (int k = 0; k < 3; ++k) {
            wh0[c][k] = W_hh0[row * 3 + k] * sc;
            wi1[c][k] = W_ih1[row * 3 + k] * sc;
            wh1[c][k] = W_hh1[row * 3 + k] * sc;
        }
        bh0[c] = b_hh0[row] * sc;
        bi1[c] = b_ih1[row] * sc;
        bh1[c] = b_hh1[row] * sc;
    }

    float h00 = 0.f, h01 = 0.f, h02 = 0.f;   // broadcast copies of h0
    float h10 = 0.f, h11 = 0.f, h12 = 0.f;   // broadcast copies of h1
    float h0j = 0.f, h1j = 0.f;              // this lane's own element

    const float* base = xw + ((size_t)s * TT) * XWS + jj * 4;

    auto LD = [&](int t) -> float4 {
        t = (t < TT) ? t : (TT - 1);          // clamped tail loads, values unused
        return *(const float4*)(base + (size_t)t * XWS);
    };

    auto STEP = [&](float4 xq) {
        // ----- layer 0 -----
        float hr = fmaf(wh0[0][2], h02, fmaf(wh0[0][1], h01, fmaf(wh0[0][0], h00, bh0[0])));
        float hz = fmaf(wh0[1][2], h02, fmaf(wh0[1][1], h01, fmaf(wh0[1][0], h00, bh0[1])));
        float hn = fmaf(wh0[2][2], h02, fmaf(wh0[2][1], h01, fmaf(wh0[2][0], h00, bh0[2])));
        float r = frcp(1.f + fexp2(xq.x + hr));                   // sigmoid
        float z = frcp(1.f + fexp2(xq.y + hz));                   // sigmoid
        float q = fmaf(r, hn, xq.z);
        float n = fmaf(-2.f, frcp(1.f + fexp2(q)), 1.f);          // tanh
        h0j = fmaf(z, h0j - n, n);
        h00 = QB0(h0j); h01 = QB1(h0j); h02 = QB2(h0j);
        // ----- layer 1 -----
        float a0 = fmaf(wi1[0][2], h02, fmaf(wi1[0][1], h01, fmaf(wi1[0][0], h00, bi1[0])));
        float a1 = fmaf(wi1[1][2], h02, fmaf(wi1[1][1], h01, fmaf(wi1[1][0], h00, bi1[1])));
        float a2 = fmaf(wi1[2][2], h02, fmaf(wi1[2][1], h01, fmaf(wi1[2][0], h00, bi1[2])));
        float g0 = fmaf(wh1[0][2], h12, fmaf(wh1[0][1], h11, fmaf(wh1[0][0], h10, bh1[0])));
        float g1 = fmaf(wh1[1][2], h12, fmaf(wh1[1][1], h11, fmaf(wh1[1][0], h10, bh1[1])));
        float g2 = fmaf(wh1[2][2], h12, fmaf(wh1[2][1], h11, fmaf(wh1[2][0], h10, bh1[2])));
        float r1 = frcp(1.f + fexp2(a0 + g0));
        float z1 = frcp(1.f + fexp2(a1 + g1));
        float q1 = fmaf(r1, g2, a2);
        float n1 = fmaf(-2.f, frcp(1.f + fexp2(q1)), 1.f);
        h1j = fmaf(z1, h1j - n1, n1);
        h10 = QB0(h1j); h11 = QB1(h1j); h12 = QB2(h1j);
    };

    float4 R0 = LD(0), R1 = LD(1), R2 = LD(2), R3 = LD(3),
           R4 = LD(4), R5 = LD(5), R6 = LD(6), R7 = LD(7);

    for (int t = 0; t < TT; t += 8) {
        STEP(R0); R0 = LD(t + 8);
        STEP(R1); R1 = LD(t + 9);
        STEP(R2); R2 = LD(t + 10);
        STEP(R3); R3 = LD(t + 11);
        STEP(R4); R4 = LD(t + 12);
        STEP(R5); R5 = LD(t + 13);
        STEP(R6); R6 = LD(t + 14);
        STEP(R7); R7 = LD(t + 15);
    }

    if (j < 3) out[s * 3 + j] = h1j;
}

// ---------------------------------------------------------------------------
extern "C" void kernel_launch(void* const* d_in, const int* in_sizes, int n_in,
                              void* d_out, int out_size, void* d_ws, size_t ws_size,
                              hipStream_t stream) {
    const float* x     = (const float*)d_in[0];
    const float* W_ih0 = (const float*)d_in[1];
    const float* W_hh0 = (const float*)d_in[2];
    const float* b_ih0 = (const float*)d_in[3];
    const float* b_hh0 = (const float*)d_in[4];
    const float* W_ih1 = (const float*)d_in[5];
    const float* W_hh1 = (const float*)d_in[6];
    const float* b_ih1 = (const float*)d_in[7];
    const float* b_hh1 = (const float*)d_in[8];
    float* out = (float*)d_out;
    float* xw  = (float*)d_ws;   // 2048*512*12*4 = 48 MiB

    hipLaunchKernelGGL(xw_kernel, dim3((BB * TT) / 1024), dim3(256), 0, stream,
                       x, W_ih0, b_ih0, xw);
    hipLaunchKernelGGL(gru_rec, dim3((BB * 4) / 64), dim3(64), 0, stream,
                       xw, W_hh0, b_hh0, W_ih1, b_ih1, W_hh1, b_hh1, out);
}